// Round 1
// baseline (125.342 us; speedup 1.0000x reference)
//
#include <hip/hip_runtime.h>
#include <hip/hip_bf16.h>

#define SEQ    2048
#define DMODEL 512
#define NH     8
#define DKH    64
#define QBLK   64
#define KVB    64
#define SCALE  0.125f

typedef __attribute__((ext_vector_type(8))) short bf16x8;
typedef __attribute__((ext_vector_type(4))) float f32x4;

__device__ __forceinline__ unsigned short f2bf(float f) {
  union { float f; unsigned u; } x; x.f = f;
  return (unsigned short)((x.u + 0x7FFFu + ((x.u >> 16) & 1u)) >> 16);
}

// XOR swizzle in bf16-element units for a [R][64] row-major tile:
// byte = r*128 + 2c, swizzled byte ^= (r&7)<<4  ->  elem = r*64 + (c ^ ((r&7)<<3))
__device__ __forceinline__ int swz(int r, int c) {
  return (r << 6) + (c ^ ((r & 7) << 3));
}

__global__ __launch_bounds__(256, 4)
void fa_fwd(const float* __restrict__ Q, const float* __restrict__ K,
            const float* __restrict__ V, float* __restrict__ O) {
  __shared__ unsigned short kt[KVB * 64];      // kt[key][d], swizzled
  __shared__ unsigned short vt[64 * KVB];      // vt[d][key] (transposed), swizzled
  __shared__ unsigned short pt[4][16 * 64];    // per-wave P tile [q][key], swizzled

  const int tid = threadIdx.x;
  const int wv  = tid >> 6;
  const int ln  = tid & 63;
  const int g   = ln >> 4;   // 0..3
  const int c   = ln & 15;   // 0..15

  const int bh = blockIdx.y;
  const size_t hoff = (size_t)(bh >> 3) * SEQ * DMODEL + (size_t)(bh & 7) * DKH;
  const float* Qh = Q + hoff;
  const float* Kh = K + hoff;
  const float* Vh = V + hoff;
  float*       Oh = O + hoff;

  // ---- load Q fragments (16 rows per wave), fold in softmax scale ----
  const int qrow = blockIdx.x * QBLK + wv * 16 + c;
  bf16x8 qf[2];
  {
    const float* qp = Qh + (size_t)qrow * DMODEL + (g << 3);
#pragma unroll
    for (int f = 0; f < 2; ++f) {
      float4 a = *(const float4*)(qp + 32 * f);
      float4 b = *(const float4*)(qp + 32 * f + 4);
      bf16x8 t;
      t[0] = (short)f2bf(a.x * SCALE); t[1] = (short)f2bf(a.y * SCALE);
      t[2] = (short)f2bf(a.z * SCALE); t[3] = (short)f2bf(a.w * SCALE);
      t[4] = (short)f2bf(b.x * SCALE); t[5] = (short)f2bf(b.y * SCALE);
      t[6] = (short)f2bf(b.z * SCALE); t[7] = (short)f2bf(b.w * SCALE);
      qf[f] = t;
    }
  }

  f32x4 oa[4] = {};                       // O accum: 4 d-subtiles (col=d=c, row=q=4g+r)
  float m_r[4], l_r[4];
#pragma unroll
  for (int r = 0; r < 4; ++r) { m_r[r] = -__builtin_inff(); l_r[r] = 0.f; }

  for (int kv0 = 0; kv0 < SEQ; kv0 += KVB) {
    // ---- stage K tile -> kt (bf16, swizzled) ----
    {
      const int r  = tid >> 2;
      const int q4 = tid & 3;
      const float* kp = Kh + (size_t)(kv0 + r) * DMODEL + (q4 << 4);
      float4 a0 = ((const float4*)kp)[0];
      float4 a1 = ((const float4*)kp)[1];
      float4 a2 = ((const float4*)kp)[2];
      float4 a3 = ((const float4*)kp)[3];
      bf16x8 w0, w1;
      w0[0]=(short)f2bf(a0.x); w0[1]=(short)f2bf(a0.y); w0[2]=(short)f2bf(a0.z); w0[3]=(short)f2bf(a0.w);
      w0[4]=(short)f2bf(a1.x); w0[5]=(short)f2bf(a1.y); w0[6]=(short)f2bf(a1.z); w0[7]=(short)f2bf(a1.w);
      w1[0]=(short)f2bf(a2.x); w1[1]=(short)f2bf(a2.y); w1[2]=(short)f2bf(a2.z); w1[3]=(short)f2bf(a2.w);
      w1[4]=(short)f2bf(a3.x); w1[5]=(short)f2bf(a3.y); w1[6]=(short)f2bf(a3.z); w1[7]=(short)f2bf(a3.w);
      *(bf16x8*)&kt[swz(r, (q4 << 4))]     = w0;
      *(bf16x8*)&kt[swz(r, (q4 << 4) + 8)] = w1;
    }
    // ---- stage V tile -> vt transposed (4x4 register-block transpose) ----
    {
      const int bi = tid >> 4;   // 0..15 -> key block
      const int bj = tid & 15;   // 0..15 -> d block
      const float* vp = Vh + (size_t)(kv0 + (bi << 2)) * DMODEL + (bj << 2);
      float4 r0 = *(const float4*)(vp);
      float4 r1 = *(const float4*)(vp + DMODEL);
      float4 r2 = *(const float4*)(vp + 2 * DMODEL);
      float4 r3 = *(const float4*)(vp + 3 * DMODEL);
#pragma unroll
      for (int cc = 0; cc < 4; ++cc) {
        ushort4 col;
        col.x = f2bf(((const float*)&r0)[cc]);
        col.y = f2bf(((const float*)&r1)[cc]);
        col.z = f2bf(((const float*)&r2)[cc]);
        col.w = f2bf(((const float*)&r3)[cc]);
        *(ushort4*)&vt[swz((bj << 2) + cc, (bi << 2))] = col;
      }
    }
    __syncthreads();

    // ---- S = Q K^T (per wave: 16q x 64key) ----
    f32x4 sa[4];
#pragma unroll
    for (int ks = 0; ks < 4; ++ks) {
      bf16x8 k0 = *(const bf16x8*)&kt[swz(ks * 16 + c, (g << 3))];
      bf16x8 k1 = *(const bf16x8*)&kt[swz(ks * 16 + c, 32 + (g << 3))];
      f32x4 acc = {0.f, 0.f, 0.f, 0.f};
      acc = __builtin_amdgcn_mfma_f32_16x16x32_bf16(qf[0], k0, acc, 0, 0, 0);
      acc = __builtin_amdgcn_mfma_f32_16x16x32_bf16(qf[1], k1, acc, 0, 0, 0);
      sa[ks] = acc;
    }

    // ---- online softmax (rows q=4g+r live in the 16-lane group) ----
#pragma unroll
    for (int r = 0; r < 4; ++r) {
      float v = fmaxf(fmaxf(sa[0][r], sa[1][r]), fmaxf(sa[2][r], sa[3][r]));
      v = fmaxf(v, __shfl_xor(v, 1));
      v = fmaxf(v, __shfl_xor(v, 2));
      v = fmaxf(v, __shfl_xor(v, 4));
      v = fmaxf(v, __shfl_xor(v, 8));
      float mn   = fmaxf(m_r[r], v);
      float corr = __expf(m_r[r] - mn);
      m_r[r] = mn;
      l_r[r] *= corr;
      oa[0][r] *= corr; oa[1][r] *= corr; oa[2][r] *= corr; oa[3][r] *= corr;
    }

    // ---- P = exp(S - m); per-lane partial row-sum; P -> LDS (bf16) ----
#pragma unroll
    for (int ks = 0; ks < 4; ++ks) {
#pragma unroll
      for (int r = 0; r < 4; ++r) {
        float p = __expf(sa[ks][r] - m_r[r]);
        l_r[r] += p;
        pt[wv][swz((g << 2) + r, ks * 16 + c)] = f2bf(p);
      }
    }

    // ---- O += P V  (A-frag from pt, B-frag from vt) ----
    bf16x8 pf0 = *(const bf16x8*)&pt[wv][swz(c, (g << 3))];
    bf16x8 pf1 = *(const bf16x8*)&pt[wv][swz(c, 32 + (g << 3))];
#pragma unroll
    for (int ds = 0; ds < 4; ++ds) {
      bf16x8 v0 = *(const bf16x8*)&vt[swz(ds * 16 + c, (g << 3))];
      bf16x8 v1 = *(const bf16x8*)&vt[swz(ds * 16 + c, 32 + (g << 3))];
      oa[ds] = __builtin_amdgcn_mfma_f32_16x16x32_bf16(pf0, v0, oa[ds], 0, 0, 0);
      oa[ds] = __builtin_amdgcn_mfma_f32_16x16x32_bf16(pf1, v1, oa[ds], 0, 0, 0);
    }
    __syncthreads();
  }

  // ---- epilogue: reduce row sums across the 16-lane group, normalize, store ----
#pragma unroll
  for (int r = 0; r < 4; ++r) {
    float v = l_r[r];
    v += __shfl_xor(v, 1);
    v += __shfl_xor(v, 2);
    v += __shfl_xor(v, 4);
    v += __shfl_xor(v, 8);
    l_r[r] = 1.0f / v;
  }
  float* op = Oh + (size_t)(blockIdx.x * QBLK + wv * 16 + (g << 2)) * DMODEL + c;
#pragma unroll
  for (int r = 0; r < 4; ++r) {
#pragma unroll
    for (int ds = 0; ds < 4; ++ds) {
      op[(size_t)r * DMODEL + ds * 16] = oa[ds][r] * l_r[r];
    }
  }
}

extern "C" void kernel_launch(void* const* d_in, const int* in_sizes, int n_in,
                              void* d_out, int out_size, void* d_ws, size_t ws_size,
                              hipStream_t stream) {
  const float* Q = (const float*)d_in[0];
  const float* K = (const float*)d_in[1];
  const float* V = (const float*)d_in[2];
  float* O = (float*)d_out;
  dim3 grid(SEQ / QBLK, 4 * NH);
  fa_fwd<<<grid, 256, 0, stream>>>(Q, K, V, O);
}

// Round 2
// 102.938 us; speedup vs baseline: 1.2176x; 1.2176x over previous
//
#include <hip/hip_runtime.h>
#include <hip/hip_bf16.h>

#define SEQ    2048
#define DMODEL 512
#define NH     8
#define QBLK   64
#define KVB    64

#if __has_builtin(__builtin_amdgcn_exp2f)
#define EXPFN(x) __builtin_amdgcn_exp2f(x)
#define QSCALE 0.18033688011112042f   /* 0.125 * log2(e) */
#else
#define EXPFN(x) __expf(x)
#define QSCALE 0.125f
#endif

typedef __attribute__((ext_vector_type(8))) short bf16x8;
typedef __attribute__((ext_vector_type(4))) float f32x4;

__device__ __forceinline__ unsigned short f2bf(float f) {
  union { float f; unsigned u; } x; x.f = f;
  return (unsigned short)((x.u + 0x7FFFu + ((x.u >> 16) & 1u)) >> 16);
}

// XOR swizzle in bf16-element units for a [R][64] row-major tile:
// elem = r*64 + (c ^ ((r&7)<<3))  (byte ^= (r&7)<<4)
__device__ __forceinline__ int swz(int r, int c) {
  return (r << 6) + (c ^ ((r & 7) << 3));
}

__device__ __forceinline__ void gload16(const void* g, void* l) {
  __builtin_amdgcn_global_load_lds(
      (const __attribute__((address_space(1))) void*)g,
      (__attribute__((address_space(3))) void*)l, 16, 0, 0);
}

// ---------------- pre-pass: K -> bf16, per-head contiguous, row-swizzled ----
// out[bh][s][d'] with d' granule g -> g ^ (s&7); one thread per 8-elem granule
__global__ void prep_k(const float* __restrict__ K, unsigned short* __restrict__ out) {
  int gid = blockIdx.x * 256 + threadIdx.x;   // 0 .. 524287
  int g  = gid & 7;
  int s  = (gid >> 3) & (SEQ - 1);
  int bh = gid >> 14;                          // 0..31
  int b = bh >> 3, h = bh & 7;
  const float* src = K + ((size_t)(b * SEQ + s) * DMODEL) + h * 64 + (g << 3);
  float4 a = ((const float4*)src)[0];
  float4 c = ((const float4*)src)[1];
  bf16x8 w;
  w[0] = (short)f2bf(a.x); w[1] = (short)f2bf(a.y);
  w[2] = (short)f2bf(a.z); w[3] = (short)f2bf(a.w);
  w[4] = (short)f2bf(c.x); w[5] = (short)f2bf(c.y);
  w[6] = (short)f2bf(c.z); w[7] = (short)f2bf(c.w);
  unsigned short* dst = out + ((size_t)bh * SEQ + s) * 64 + ((g ^ (s & 7)) << 3);
  *(bf16x8*)dst = w;
}

// -------- pre-pass: V -> bf16 transposed per 64-key tile, row-swizzled ------
// out[bh][tile][d][k'] ; k granule m -> m ^ (d&7). block = one (bh,tile)
__global__ void prep_v(const float* __restrict__ V, unsigned short* __restrict__ out) {
  int bt = blockIdx.x;            // bh*32 + tile
  int bh = bt >> 5, tile = bt & 31;
  int b = bh >> 3, h = bh & 7;
  int t  = threadIdx.x;
  int d  = t >> 2;                // 0..63
  int kg = t & 3;                 // 0..3 (16 keys each)
  const float* src = V + ((size_t)(b * SEQ + tile * 64 + kg * 16) * DMODEL) + h * 64 + d;
  float v[16];
#pragma unroll
  for (int j = 0; j < 16; ++j) v[j] = src[(size_t)j * DMODEL];
  bf16x8 lo, hi;
#pragma unroll
  for (int j = 0; j < 8; ++j) { lo[j] = (short)f2bf(v[j]); hi[j] = (short)f2bf(v[8 + j]); }
  unsigned short* row = out + ((size_t)bt * 64 + d) * 64;
  *(bf16x8*)(row + ((((kg << 1))     ^ (d & 7)) << 3)) = lo;
  *(bf16x8*)(row + ((((kg << 1) | 1) ^ (d & 7)) << 3)) = hi;
}

// ---------------------------- main attention --------------------------------
__global__ __launch_bounds__(256, 4)
void fa_fwd(const float* __restrict__ Q, const unsigned short* __restrict__ Kb,
            const unsigned short* __restrict__ Vb, float* __restrict__ O) {
  __shared__ unsigned short kt[2][KVB * 64];
  __shared__ unsigned short vt[2][64 * KVB];
  __shared__ unsigned short pt[4][16 * 64];

  const int tid = threadIdx.x;
  const int wv  = tid >> 6;
  const int ln  = tid & 63;
  const int g   = ln >> 4;
  const int c   = ln & 15;

  // XCD-chunked swizzle: XCD x gets heads 4x..4x+3 (K/V panels stay in its L2)
  const int orig = blockIdx.x;
  const int wgid = (orig & 7) * 128 + (orig >> 3);
  const int bh = wgid >> 5;
  const int qt = wgid & 31;

  const int b = bh >> 3, h = bh & 7;
  const float* Qh = Q + (size_t)b * SEQ * DMODEL + (size_t)h * 64;
  float*       Oh = O + (size_t)b * SEQ * DMODEL + (size_t)h * 64;
  const unsigned short* Kh = Kb + (size_t)bh * SEQ * 64;
  const unsigned short* Vh = Vb + (size_t)bh * 32 * 4096;

  // ---- Q fragments (16 rows/wave), scale folded ----
  const int qrow = qt * QBLK + wv * 16 + c;
  bf16x8 qf[2];
  {
    const float* qp = Qh + (size_t)qrow * DMODEL + (g << 3);
#pragma unroll
    for (int f = 0; f < 2; ++f) {
      float4 a = *(const float4*)(qp + 32 * f);
      float4 d4 = *(const float4*)(qp + 32 * f + 4);
      bf16x8 t;
      t[0] = (short)f2bf(a.x * QSCALE);  t[1] = (short)f2bf(a.y * QSCALE);
      t[2] = (short)f2bf(a.z * QSCALE);  t[3] = (short)f2bf(a.w * QSCALE);
      t[4] = (short)f2bf(d4.x * QSCALE); t[5] = (short)f2bf(d4.y * QSCALE);
      t[6] = (short)f2bf(d4.z * QSCALE); t[7] = (short)f2bf(d4.w * QSCALE);
      qf[f] = t;
    }
  }

  f32x4 oa[4] = {};
  float m_r[4], l_r[4];
#pragma unroll
  for (int r = 0; r < 4; ++r) { m_r[r] = -__builtin_inff(); l_r[r] = 0.f; }

  // stage: 8KB K + 8KB V; 4 waves x 2 chunks of 1KB each, linear LDS dest
#define STAGE(T, B)                                                        \
  do {                                                                     \
    const char* gk = (const char*)(Kh + (size_t)(T) * KVB * 64);           \
    const char* gv = (const char*)(Vh + (size_t)(T) * 4096);               \
    char* lk = (char*)&kt[(B)][0];                                         \
    char* lv = (char*)&vt[(B)][0];                                         \
    gload16(gk + (((wv)     * 64 + ln) << 4), lk + ((wv)     << 10));      \
    gload16(gk + (((wv + 4) * 64 + ln) << 4), lk + ((wv + 4) << 10));      \
    gload16(gv + (((wv)     * 64 + ln) << 4), lv + ((wv)     << 10));      \
    gload16(gv + (((wv + 4) * 64 + ln) << 4), lv + ((wv + 4) << 10));      \
  } while (0)

  STAGE(0, 0);
  __syncthreads();

  int bb = 0;
  for (int t = 0; t < SEQ / KVB; ++t) {
    if (t + 1 < SEQ / KVB) STAGE(t + 1, bb ^ 1);

    // ---- S = Q K^T ----
    f32x4 sa[4];
#pragma unroll
    for (int ks = 0; ks < 4; ++ks) {
      bf16x8 k0 = *(const bf16x8*)&kt[bb][swz(ks * 16 + c, (g << 3))];
      bf16x8 k1 = *(const bf16x8*)&kt[bb][swz(ks * 16 + c, 32 + (g << 3))];
      f32x4 acc = {0.f, 0.f, 0.f, 0.f};
      acc = __builtin_amdgcn_mfma_f32_16x16x32_bf16(qf[0], k0, acc, 0, 0, 0);
      acc = __builtin_amdgcn_mfma_f32_16x16x32_bf16(qf[1], k1, acc, 0, 0, 0);
      sa[ks] = acc;
    }

    // ---- online softmax ----
#pragma unroll
    for (int r = 0; r < 4; ++r) {
      float v = fmaxf(fmaxf(sa[0][r], sa[1][r]), fmaxf(sa[2][r], sa[3][r]));
      v = fmaxf(v, __shfl_xor(v, 1));
      v = fmaxf(v, __shfl_xor(v, 2));
      v = fmaxf(v, __shfl_xor(v, 4));
      v = fmaxf(v, __shfl_xor(v, 8));
      float mn   = fmaxf(m_r[r], v);
      float corr = EXPFN(m_r[r] - mn);
      m_r[r] = mn;
      l_r[r] *= corr;
      oa[0][r] *= corr; oa[1][r] *= corr; oa[2][r] *= corr; oa[3][r] *= corr;
    }

    // ---- P = exp(S - m); partial row-sums; P -> LDS bf16 ----
#pragma unroll
    for (int ks = 0; ks < 4; ++ks) {
#pragma unroll
      for (int r = 0; r < 4; ++r) {
        float p = EXPFN(sa[ks][r] - m_r[r]);
        l_r[r] += p;
        pt[wv][swz((g << 2) + r, ks * 16 + c)] = f2bf(p);
      }
    }

    // ---- O += P V ----
    bf16x8 pf0 = *(const bf16x8*)&pt[wv][swz(c, (g << 3))];
    bf16x8 pf1 = *(const bf16x8*)&pt[wv][swz(c, 32 + (g << 3))];
#pragma unroll
    for (int ds = 0; ds < 4; ++ds) {
      bf16x8 v0 = *(const bf16x8*)&vt[bb][swz(ds * 16 + c, (g << 3))];
      bf16x8 v1 = *(const bf16x8*)&vt[bb][swz(ds * 16 + c, 32 + (g << 3))];
      oa[ds] = __builtin_amdgcn_mfma_f32_16x16x32_bf16(pf0, v0, oa[ds], 0, 0, 0);
      oa[ds] = __builtin_amdgcn_mfma_f32_16x16x32_bf16(pf1, v1, oa[ds], 0, 0, 0);
    }
    __syncthreads();
    bb ^= 1;
  }

  // ---- epilogue ----
#pragma unroll
  for (int r = 0; r < 4; ++r) {
    float v = l_r[r];
    v += __shfl_xor(v, 1);
    v += __shfl_xor(v, 2);
    v += __shfl_xor(v, 4);
    v += __shfl_xor(v, 8);
    l_r[r] = 1.0f / v;
  }
  float* op = Oh + (size_t)(qt * QBLK + wv * 16 + (g << 2)) * DMODEL + c;
#pragma unroll
  for (int r = 0; r < 4; ++r) {
#pragma unroll
    for (int ds = 0; ds < 4; ++ds) {
      op[(size_t)r * DMODEL + ds * 16] = oa[ds][r] * l_r[r];
    }
  }
}

// ------------------- legacy fallback (round-1 kernel, f32 inputs) -----------
__global__ __launch_bounds__(256, 4)
void fa_fwd_legacy(const float* __restrict__ Q, const float* __restrict__ K,
                   const float* __restrict__ V, float* __restrict__ O) {
  __shared__ unsigned short kt[KVB * 64];
  __shared__ unsigned short vt[64 * KVB];
  __shared__ unsigned short pt[4][16 * 64];

  const int tid = threadIdx.x;
  const int wv  = tid >> 6;
  const int ln  = tid & 63;
  const int g   = ln >> 4;
  const int c   = ln & 15;

  const int bh = blockIdx.y;
  const size_t hoff = (size_t)(bh >> 3) * SEQ * DMODEL + (size_t)(bh & 7) * 64;
  const float* Qh = Q + hoff;
  const float* Kh = K + hoff;
  const float* Vh = V + hoff;
  float*       Oh = O + hoff;

  const int qrow = blockIdx.x * QBLK + wv * 16 + c;
  bf16x8 qf[2];
  {
    const float* qp = Qh + (size_t)qrow * DMODEL + (g << 3);
#pragma unroll
    for (int f = 0; f < 2; ++f) {
      float4 a = *(const float4*)(qp + 32 * f);
      float4 b = *(const float4*)(qp + 32 * f + 4);
      bf16x8 t;
      t[0] = (short)f2bf(a.x * QSCALE); t[1] = (short)f2bf(a.y * QSCALE);
      t[2] = (short)f2bf(a.z * QSCALE); t[3] = (short)f2bf(a.w * QSCALE);
      t[4] = (short)f2bf(b.x * QSCALE); t[5] = (short)f2bf(b.y * QSCALE);
      t[6] = (short)f2bf(b.z * QSCALE); t[7] = (short)f2bf(b.w * QSCALE);
      qf[f] = t;
    }
  }

  f32x4 oa[4] = {};
  float m_r[4], l_r[4];
#pragma unroll
  for (int r = 0; r < 4; ++r) { m_r[r] = -__builtin_inff(); l_r[r] = 0.f; }

  for (int kv0 = 0; kv0 < SEQ; kv0 += KVB) {
    {
      const int r  = tid >> 2;
      const int q4 = tid & 3;
      const float* kp = Kh + (size_t)(kv0 + r) * DMODEL + (q4 << 4);
      float4 a0 = ((const float4*)kp)[0];
      float4 a1 = ((const float4*)kp)[1];
      float4 a2 = ((const float4*)kp)[2];
      float4 a3 = ((const float4*)kp)[3];
      bf16x8 w0, w1;
      w0[0]=(short)f2bf(a0.x); w0[1]=(short)f2bf(a0.y); w0[2]=(short)f2bf(a0.z); w0[3]=(short)f2bf(a0.w);
      w0[4]=(short)f2bf(a1.x); w0[5]=(short)f2bf(a1.y); w0[6]=(short)f2bf(a1.z); w0[7]=(short)f2bf(a1.w);
      w1[0]=(short)f2bf(a2.x); w1[1]=(short)f2bf(a2.y); w1[2]=(short)f2bf(a2.z); w1[3]=(short)f2bf(a2.w);
      w1[4]=(short)f2bf(a3.x); w1[5]=(short)f2bf(a3.y); w1[6]=(short)f2bf(a3.z); w1[7]=(short)f2bf(a3.w);
      *(bf16x8*)&kt[swz(r, (q4 << 4))]     = w0;
      *(bf16x8*)&kt[swz(r, (q4 << 4) + 8)] = w1;
    }
    {
      const int bi = tid >> 4;
      const int bj = tid & 15;
      const float* vp = Vh + (size_t)(kv0 + (bi << 2)) * DMODEL + (bj << 2);
      float4 r0 = *(const float4*)(vp);
      float4 r1 = *(const float4*)(vp + DMODEL);
      float4 r2 = *(const float4*)(vp + 2 * DMODEL);
      float4 r3 = *(const float4*)(vp + 3 * DMODEL);
#pragma unroll
      for (int cc = 0; cc < 4; ++cc) {
        ushort4 col;
        col.x = f2bf(((const float*)&r0)[cc]);
        col.y = f2bf(((const float*)&r1)[cc]);
        col.z = f2bf(((const float*)&r2)[cc]);
        col.w = f2bf(((const float*)&r3)[cc]);
        *(ushort4*)&vt[swz((bj << 2) + cc, (bi << 2))] = col;
      }
    }
    __syncthreads();

    f32x4 sa[4];
#pragma unroll
    for (int ks = 0; ks < 4; ++ks) {
      bf16x8 k0 = *(const bf16x8*)&kt[swz(ks * 16 + c, (g << 3))];
      bf16x8 k1 = *(const bf16x8*)&kt[swz(ks * 16 + c, 32 + (g << 3))];
      f32x4 acc = {0.f, 0.f, 0.f, 0.f};
      acc = __builtin_amdgcn_mfma_f32_16x16x32_bf16(qf[0], k0, acc, 0, 0, 0);
      acc = __builtin_amdgcn_mfma_f32_16x16x32_bf16(qf[1], k1, acc, 0, 0, 0);
      sa[ks] = acc;
    }

#pragma unroll
    for (int r = 0; r < 4; ++r) {
      float v = fmaxf(fmaxf(sa[0][r], sa[1][r]), fmaxf(sa[2][r], sa[3][r]));
      v = fmaxf(v, __shfl_xor(v, 1));
      v = fmaxf(v, __shfl_xor(v, 2));
      v = fmaxf(v, __shfl_xor(v, 4));
      v = fmaxf(v, __shfl_xor(v, 8));
      float mn   = fmaxf(m_r[r], v);
      float corr = EXPFN(m_r[r] - mn);
      m_r[r] = mn;
      l_r[r] *= corr;
      oa[0][r] *= corr; oa[1][r] *= corr; oa[2][r] *= corr; oa[3][r] *= corr;
    }

#pragma unroll
    for (int ks = 0; ks < 4; ++ks) {
#pragma unroll
      for (int r = 0; r < 4; ++r) {
        float p = EXPFN(sa[ks][r] - m_r[r]);
        l_r[r] += p;
        pt[wv][swz((g << 2) + r, ks * 16 + c)] = f2bf(p);
      }
    }

    bf16x8 pf0 = *(const bf16x8*)&pt[wv][swz(c, (g << 3))];
    bf16x8 pf1 = *(const bf16x8*)&pt[wv][swz(c, 32 + (g << 3))];
#pragma unroll
    for (int ds = 0; ds < 4; ++ds) {
      bf16x8 v0 = *(const bf16x8*)&vt[swz(ds * 16 + c, (g << 3))];
      bf16x8 v1 = *(const bf16x8*)&vt[swz(ds * 16 + c, 32 + (g << 3))];
      oa[ds] = __builtin_amdgcn_mfma_f32_16x16x32_bf16(pf0, v0, oa[ds], 0, 0, 0);
      oa[ds] = __builtin_amdgcn_mfma_f32_16x16x32_bf16(pf1, v1, oa[ds], 0, 0, 0);
    }
    __syncthreads();
  }

#pragma unroll
  for (int r = 0; r < 4; ++r) {
    float v = l_r[r];
    v += __shfl_xor(v, 1);
    v += __shfl_xor(v, 2);
    v += __shfl_xor(v, 4);
    v += __shfl_xor(v, 8);
    l_r[r] = 1.0f / v;
  }
  float* op = Oh + (size_t)(blockIdx.x * QBLK + wv * 16 + (g << 2)) * DMODEL + c;
#pragma unroll
  for (int r = 0; r < 4; ++r) {
#pragma unroll
    for (int ds = 0; ds < 4; ++ds) {
      op[(size_t)r * DMODEL + ds * 16] = oa[ds][r] * l_r[r];
    }
  }
}

extern "C" void kernel_launch(void* const* d_in, const int* in_sizes, int n_in,
                              void* d_out, int out_size, void* d_ws, size_t ws_size,
                              hipStream_t stream) {
  const float* Q = (const float*)d_in[0];
  const float* K = (const float*)d_in[1];
  const float* V = (const float*)d_in[2];
  float* O = (float*)d_out;
  const size_t need = (size_t)2 * 32 * SEQ * 64 * sizeof(unsigned short);  // 16 MB
  if (ws_size >= need) {
    unsigned short* kb = (unsigned short*)d_ws;
    unsigned short* vb = kb + (size_t)32 * SEQ * 64;
    prep_k<<<2048, 256, 0, stream>>>(K, kb);
    prep_v<<<1024, 256, 0, stream>>>(V, vb);
    fa_fwd<<<1024, 256, 0, stream>>>(Q, kb, vb, O);
  } else {
    dim3 grid(SEQ / QBLK, 4 * NH);
    fa_fwd_legacy<<<grid, 256, 0, stream>>>(Q, K, V, O);
  }
}

// Round 3
// 68.385 us; speedup vs baseline: 1.8329x; 1.5053x over previous
//
#include <hip/hip_runtime.h>
#include <hip/hip_bf16.h>

#define SEQ    2048
#define DMODEL 512
#define NH     8
#define QBLK   128   /* 4 waves x 32 q-rows */
#define KVB    64

#if __has_builtin(__builtin_amdgcn_exp2f)
#define EXPFN(x) __builtin_amdgcn_exp2f(x)
#define QSCALE 0.18033688011112042f   /* 0.125 * log2(e) */
#else
#define EXPFN(x) __expf(x)
#define QSCALE 0.125f
#endif
#define THR 8.0f

typedef __attribute__((ext_vector_type(8)))  short bf16x8;
typedef __attribute__((ext_vector_type(4)))  float f32x4;
typedef __attribute__((ext_vector_type(16))) float f32x16;
typedef __attribute__((ext_vector_type(2)))  int   i32x2;

#define MFMA32(A, B, C) __builtin_amdgcn_mfma_f32_32x32x16_bf16(A, B, C, 0, 0, 0)

__device__ __forceinline__ unsigned short f2bf(float f) {
  union { float f; unsigned u; } x; x.f = f;
  return (unsigned short)((x.u + 0x7FFFu + ((x.u >> 16) & 1u)) >> 16);
}

__device__ __forceinline__ int cvtpk(float lo, float hi) {
  int r;
  asm("v_cvt_pk_bf16_f32 %0, %1, %2" : "=v"(r) : "v"(lo), "v"(hi));
  return r;
}

// swap: out.x = {A.lo, B.lo-as-seen-by-hi}; out.y = {A.hi, B.hi}
__device__ __forceinline__ i32x2 plswap(int a, int b) {
#if __has_builtin(__builtin_amdgcn_permlane32_swap)
  return __builtin_amdgcn_permlane32_swap(a, b, false, false);
#else
  int a2 = __shfl_xor(a, 32), b2 = __shfl_xor(b, 32);
  int hi = (threadIdx.x >> 5) & 1;
  i32x2 r; r.x = hi ? b2 : a; r.y = hi ? b : a2; return r;
#endif
}

// XOR swizzle (elements) for [R][64] bf16 tiles: granule g -> g ^ (r&7)
__device__ __forceinline__ int swz(int r, int c) {
  return (r << 6) + (c ^ ((r & 7) << 3));
}

__device__ __forceinline__ void gload16(const void* g, void* l) {
  __builtin_amdgcn_global_load_lds(
      (const __attribute__((address_space(1))) void*)g,
      (__attribute__((address_space(3))) void*)l, 16, 0, 0);
}

// ---------------- pre-pass: K -> bf16, per-head contiguous, row-swizzled ----
__global__ void prep_k(const float* __restrict__ K, unsigned short* __restrict__ out) {
  int gid = blockIdx.x * 256 + threadIdx.x;
  int g  = gid & 7;
  int s  = (gid >> 3) & (SEQ - 1);
  int bh = gid >> 14;
  int b = bh >> 3, h = bh & 7;
  const float* src = K + ((size_t)(b * SEQ + s) * DMODEL) + h * 64 + (g << 3);
  float4 a = ((const float4*)src)[0];
  float4 c = ((const float4*)src)[1];
  bf16x8 w;
  w[0] = (short)f2bf(a.x); w[1] = (short)f2bf(a.y);
  w[2] = (short)f2bf(a.z); w[3] = (short)f2bf(a.w);
  w[4] = (short)f2bf(c.x); w[5] = (short)f2bf(c.y);
  w[6] = (short)f2bf(c.z); w[7] = (short)f2bf(c.w);
  unsigned short* dst = out + ((size_t)bh * SEQ + s) * 64 + ((g ^ (s & 7)) << 3);
  *(bf16x8*)dst = w;
}

// -------- pre-pass: V -> bf16 transposed per 64-key tile, row-swizzled ------
__global__ void prep_v(const float* __restrict__ V, unsigned short* __restrict__ out) {
  int bt = blockIdx.x;            // bh*32 + tile
  int bh = bt >> 5, tile = bt & 31;
  int b = bh >> 3, h = bh & 7;
  int t  = threadIdx.x;
  int d  = t >> 2;                // 0..63
  int kg = t & 3;                 // 16 keys each
  const float* src = V + ((size_t)(b * SEQ + tile * 64 + kg * 16) * DMODEL) + h * 64 + d;
  float v[16];
#pragma unroll
  for (int j = 0; j < 16; ++j) v[j] = src[(size_t)j * DMODEL];
  bf16x8 lo, hi;
#pragma unroll
  for (int j = 0; j < 8; ++j) { lo[j] = (short)f2bf(v[j]); hi[j] = (short)f2bf(v[8 + j]); }
  unsigned short* row = out + ((size_t)bt * 64 + d) * 64;
  *(bf16x8*)(row + ((((kg << 1))     ^ (d & 7)) << 3)) = lo;
  *(bf16x8*)(row + ((((kg << 1) | 1) ^ (d & 7)) << 3)) = hi;
}

// ---------------------------- main attention --------------------------------
__global__ __launch_bounds__(256, 2)
void fa_fwd(const float* __restrict__ Q, const unsigned short* __restrict__ Kb,
            const unsigned short* __restrict__ Vb, float* __restrict__ O) {
  __shared__ unsigned short kt[2][KVB * 64];
  __shared__ unsigned short vt[2][64 * KVB];

  const int tid = threadIdx.x;
  const int wv  = tid >> 6;
  const int ln  = tid & 63;
  const int l31 = ln & 31;
  const int hi  = ln >> 5;

  // XCD-chunked swizzle (512 blocks, 64 per XCD -> 4 heads per XCD L2)
  const int orig = blockIdx.x;
  const int wgid = (orig & 7) * 64 + (orig >> 3);
  const int bh = wgid >> 4;
  const int qt = wgid & 15;
  const int b = bh >> 3, h = bh & 7;

  const float* Qh = Q + (size_t)b * SEQ * DMODEL + (size_t)h * 64;
  float*       Oh = O + (size_t)b * SEQ * DMODEL + (size_t)h * 64;
  const unsigned short* Kh = Kb + (size_t)bh * SEQ * 64;
  const unsigned short* Vh = Vb + (size_t)bh * SEQ * 64;

  const int q = qt * QBLK + wv * 32 + l31;

  // ---- Q fragments: lane holds Q[q][16t+8hi+j], j=0..7, per k-step t ----
  bf16x8 qf[4];
  {
    const float* qp = Qh + (size_t)q * DMODEL + (hi << 3);
#pragma unroll
    for (int t = 0; t < 4; ++t) {
      float4 a = *(const float4*)(qp + 16 * t);
      float4 c = *(const float4*)(qp + 16 * t + 4);
      bf16x8 w;
      w[0] = (short)f2bf(a.x * QSCALE); w[1] = (short)f2bf(a.y * QSCALE);
      w[2] = (short)f2bf(a.z * QSCALE); w[3] = (short)f2bf(a.w * QSCALE);
      w[4] = (short)f2bf(c.x * QSCALE); w[5] = (short)f2bf(c.y * QSCALE);
      w[6] = (short)f2bf(c.z * QSCALE); w[7] = (short)f2bf(c.w * QSCALE);
      qf[t] = w;
    }
  }

  // col-granule byte-ish offsets (element units) for swizzled frag reads
  int cg[4];
#pragma unroll
  for (int t = 0; t < 4; ++t) cg[t] = (((2 * t + hi) ^ (ln & 7)) << 3);

  f32x16 o0 = {}, o1 = {};    // O^T: rows d=(reg&3)+8(reg>>2)+4hi (+32 for o1), col q=l31
  float m = -__builtin_inff();
  float l = 0.f;

#define STAGE(T, B)                                                        \
  do {                                                                     \
    const char* gk = (const char*)(Kh + (size_t)(T) * KVB * 64);           \
    const char* gv = (const char*)(Vh + (size_t)(T) * KVB * 64);           \
    char* lk = (char*)&kt[(B)][0];                                         \
    char* lv = (char*)&vt[(B)][0];                                         \
    gload16(gk + (((wv)     * 64 + ln) << 4), lk + ((wv)     << 10));      \
    gload16(gk + (((wv + 4) * 64 + ln) << 4), lk + ((wv + 4) << 10));      \
    gload16(gv + (((wv)     * 64 + ln) << 4), lv + ((wv)     << 10));      \
    gload16(gv + (((wv + 4) * 64 + ln) << 4), lv + ((wv + 4) << 10));      \
  } while (0)

  STAGE(0, 0);
  __syncthreads();

  int bb = 0;
  for (int t = 0; t < SEQ / KVB; ++t) {
    if (t + 1 < SEQ / KVB) STAGE(t + 1, bb ^ 1);
    const unsigned short* ktb = kt[bb];
    const unsigned short* vtb = vt[bb];

    // ---- S^T = K Q^T : rows=key(64, two mfma groups), cols=q(32) ----
    f32x16 s0 = {}, s1 = {};
#pragma unroll
    for (int ks = 0; ks < 4; ++ks) {
      bf16x8 k0 = *(const bf16x8*)&ktb[(l31 << 6) + cg[ks]];
      bf16x8 k1 = *(const bf16x8*)&ktb[((l31 + 32) << 6) + cg[ks]];
      s0 = MFMA32(k0, qf[ks], s0);
      s1 = MFMA32(k1, qf[ks], s1);
    }

    // ---- per-lane (one q-row) online softmax ----
    float pm = s0[0];
#pragma unroll
    for (int j = 1; j < 16; ++j) pm = fmaxf(pm, s0[j]);
#pragma unroll
    for (int j = 0; j < 16; ++j) pm = fmaxf(pm, s1[j]);
    pm = fmaxf(pm, __shfl_xor(pm, 32));

    if (__any(pm > m + THR)) {
      float mn   = fmaxf(m, pm);
      float corr = EXPFN(m - mn);
      m = mn;
      l *= corr;
#pragma unroll
      for (int j = 0; j < 16; ++j) { o0[j] *= corr; o1[j] *= corr; }
    }

    // ---- P = exp(S - m); pack to PV B-fragments via cvt_pk + permlane ----
#pragma unroll
    for (int ks = 0; ks < 4; ++ks) {
      float e[8];
#pragma unroll
      for (int j = 0; j < 8; ++j) {
        float sv = (ks < 2) ? s0[(ks & 1) * 8 + j] : s1[(ks & 1) * 8 + j];
        e[j] = EXPFN(sv - m);
      }
      l += ((e[0] + e[1]) + (e[2] + e[3])) + ((e[4] + e[5]) + (e[6] + e[7]));
      i32x2 r0 = plswap(cvtpk(e[0], e[1]), cvtpk(e[4], e[5]));
      i32x2 r1 = plswap(cvtpk(e[2], e[3]), cvtpk(e[6], e[7]));
      union { int i[4]; bf16x8 v; } pa;
      pa.i[0] = r0.x; pa.i[1] = r1.x; pa.i[2] = r0.y; pa.i[3] = r1.y;

      bf16x8 v0 = *(const bf16x8*)&vtb[(l31 << 6) + cg[ks]];
      bf16x8 v1 = *(const bf16x8*)&vtb[((l31 + 32) << 6) + cg[ks]];
      o0 = MFMA32(v0, pa.v, o0);   // O^T[d 0..31][q]
      o1 = MFMA32(v1, pa.v, o1);   // O^T[d 32..63][q]
    }
    __syncthreads();
    bb ^= 1;
  }

  // ---- epilogue: combine halves' l, normalize, store ----
  l += __shfl_xor(l, 32);
  float rinv = 1.0f / l;
  float* op = Oh + (size_t)q * DMODEL;
#pragma unroll
  for (int r4 = 0; r4 < 4; ++r4) {
    float4 w0, w1;
    w0.x = o0[4 * r4 + 0] * rinv; w0.y = o0[4 * r4 + 1] * rinv;
    w0.z = o0[4 * r4 + 2] * rinv; w0.w = o0[4 * r4 + 3] * rinv;
    w1.x = o1[4 * r4 + 0] * rinv; w1.y = o1[4 * r4 + 1] * rinv;
    w1.z = o1[4 * r4 + 2] * rinv; w1.w = o1[4 * r4 + 3] * rinv;
    *(float4*)(op + 8 * r4 + 4 * hi)      = w0;
    *(float4*)(op + 32 + 8 * r4 + 4 * hi) = w1;
  }
}

extern "C" void kernel_launch(void* const* d_in, const int* in_sizes, int n_in,
                              void* d_out, int out_size, void* d_ws, size_t ws_size,
                              hipStream_t stream) {
  const float* Q = (const float*)d_in[0];
  const float* K = (const float*)d_in[1];
  const float* V = (const float*)d_in[2];
  float* O = (float*)d_out;
  unsigned short* kb = (unsigned short*)d_ws;
  unsigned short* vb = kb + (size_t)32 * SEQ * 64;
  prep_k<<<2048, 256, 0, stream>>>(K, kb);
  prep_v<<<1024, 256, 0, stream>>>(V, vb);
  fa_fwd<<<512, 256, 0, stream>>>(Q, kb, vb, O);
}

// Round 4
// 63.117 us; speedup vs baseline: 1.9859x; 1.0835x over previous
//
#include <hip/hip_runtime.h>
#include <hip/hip_bf16.h>

#define SEQ    2048
#define DMODEL 512
#define NH     8
#define QBLK   128   /* 4 waves x 32 q-rows */
#define KVB    64

#if __has_builtin(__builtin_amdgcn_exp2f)
#define EXPFN(x) __builtin_amdgcn_exp2f(x)
#define QSCALE 0.18033688011112042f   /* 0.125 * log2(e) */
#else
#define EXPFN(x) __expf(x)
#define QSCALE 0.125f
#endif
#define THR 8.0f

typedef __attribute__((ext_vector_type(8)))  short bf16x8;
typedef __attribute__((ext_vector_type(16))) float f32x16;
typedef __attribute__((ext_vector_type(2)))  int   i32x2;

#define MFMA32(A, B, C) __builtin_amdgcn_mfma_f32_32x32x16_bf16(A, B, C, 0, 0, 0)

__device__ __forceinline__ unsigned short f2bf(float f) {
  union { float f; unsigned u; } x; x.f = f;
  return (unsigned short)((x.u + 0x7FFFu + ((x.u >> 16) & 1u)) >> 16);
}

__device__ __forceinline__ int cvtpk(float lo, float hi) {
  int r;
  asm("v_cvt_pk_bf16_f32 %0, %1, %2" : "=v"(r) : "v"(lo), "v"(hi));
  return r;
}

__device__ __forceinline__ i32x2 plswap(int a, int b) {
#if __has_builtin(__builtin_amdgcn_permlane32_swap)
  return __builtin_amdgcn_permlane32_swap(a, b, false, false);
#else
  int a2 = __shfl_xor(a, 32), b2 = __shfl_xor(b, 32);
  int hi = (threadIdx.x >> 5) & 1;
  i32x2 r; r.x = hi ? b2 : a; r.y = hi ? b : a2; return r;
#endif
}

__device__ __forceinline__ void gload16(const void* g, void* l) {
  __builtin_amdgcn_global_load_lds(
      (const __attribute__((address_space(1))) void*)g,
      (__attribute__((address_space(3))) void*)l, 16, 0, 0);
}

// ---------------------------------------------------------------------------
// Tile layout (both K and V^T): 8KB tile = 32 LDS rows x 256B.
// Row r' = r & 31 holds rows r' and r'+32.  16B slot within the 256B row:
//   slot(r, g) = (((r>>5)<<3) + g) ^ (r & 15),  g = 16B granule 0..7.
// Every 16-lane ds_read_b128 phase reads 16 distinct slots -> conflict-free.
// ---------------------------------------------------------------------------

// fused pre-pass: blocks [0,2048) convert K, [2048,3072) transpose V
__global__ void prep_kv(const float* __restrict__ K, const float* __restrict__ V,
                        unsigned short* __restrict__ kb, unsigned short* __restrict__ vb) {
  if (blockIdx.x < 2048) {
    int gid = blockIdx.x * 256 + threadIdx.x;
    int g  = gid & 7;
    int s  = (gid >> 3) & (SEQ - 1);
    int bh = gid >> 14;
    int b = bh >> 3, h = bh & 7;
    const float* src = K + ((size_t)(b * SEQ + s) * DMODEL) + h * 64 + (g << 3);
    float4 a = ((const float4*)src)[0];
    float4 c = ((const float4*)src)[1];
    bf16x8 w;
    w[0] = (short)f2bf(a.x); w[1] = (short)f2bf(a.y);
    w[2] = (short)f2bf(a.z); w[3] = (short)f2bf(a.w);
    w[4] = (short)f2bf(c.x); w[5] = (short)f2bf(c.y);
    w[6] = (short)f2bf(c.z); w[7] = (short)f2bf(c.w);
    int r = s & 63;
    int slot = ((((r >> 5) << 3) + g) ^ (r & 15));
    unsigned short* dst = kb + ((size_t)bh * SEQ + (s & ~63)) * 64
                             + ((r & 31) << 7) + (slot << 3);
    *(bf16x8*)dst = w;
  } else {
    int bt = blockIdx.x - 2048;     // bh*32 + tile
    int bh = bt >> 5, tile = bt & 31;
    int b = bh >> 3, h = bh & 7;
    int t  = threadIdx.x;
    int d  = t & 63;                // coalesced: lanes read consecutive d
    int kg = t >> 6;                // 0..3 -> keys kg*16 .. +15
    const float* src = V + ((size_t)(b * SEQ + tile * 64 + kg * 16) * DMODEL) + h * 64 + d;
    float v[16];
#pragma unroll
    for (int j = 0; j < 16; ++j) v[j] = src[(size_t)j * DMODEL];
    bf16x8 lo, hi;
#pragma unroll
    for (int j = 0; j < 8; ++j) { lo[j] = (short)f2bf(v[j]); hi[j] = (short)f2bf(v[8 + j]); }
    unsigned short* base = vb + ((size_t)bt << 12);
    int g0 = kg << 1, g1 = (kg << 1) | 1;
    int rb = (((d >> 5) << 3));
    int s0 = ((rb + g0) ^ (d & 15));
    int s1 = ((rb + g1) ^ (d & 15));
    unsigned short* row = base + ((d & 31) << 7);
    *(bf16x8*)(row + (s0 << 3)) = lo;
    *(bf16x8*)(row + (s1 << 3)) = hi;
  }
}

// ---------------------------- main attention --------------------------------
__global__ __launch_bounds__(256, 2)
void fa_fwd(const float* __restrict__ Q, const unsigned short* __restrict__ Kb,
            const unsigned short* __restrict__ Vb, float* __restrict__ O) {
  __shared__ unsigned short kt[2][KVB * 64];
  __shared__ unsigned short vt[2][64 * KVB];

  const int tid = threadIdx.x;
  const int wv  = tid >> 6;
  const int ln  = tid & 63;
  const int l31 = ln & 31;
  const int hi  = ln >> 5;

  // XCD-chunked swizzle (512 blocks, 64 per XCD -> 4 heads per XCD L2)
  const int orig = blockIdx.x;
  const int wgid = (orig & 7) * 64 + (orig >> 3);
  const int bh = wgid >> 4;
  const int qt = wgid & 15;
  const int b = bh >> 3, h = bh & 7;

  const float* Qh = Q + (size_t)b * SEQ * DMODEL + (size_t)h * 64;
  float*       Oh = O + (size_t)b * SEQ * DMODEL + (size_t)h * 64;
  const unsigned short* Kh = Kb + (size_t)bh * SEQ * 64;
  const unsigned short* Vh = Vb + (size_t)bh * SEQ * 64;

  const int q = qt * QBLK + wv * 32 + l31;

  // ---- Q fragments: lane holds Q[q][16t+8hi+j], j=0..7 ----
  bf16x8 qf[4];
  {
    const float* qp = Qh + (size_t)q * DMODEL + (hi << 3);
#pragma unroll
    for (int t = 0; t < 4; ++t) {
      float4 a = *(const float4*)(qp + 16 * t);
      float4 c = *(const float4*)(qp + 16 * t + 4);
      bf16x8 w;
      w[0] = (short)f2bf(a.x * QSCALE); w[1] = (short)f2bf(a.y * QSCALE);
      w[2] = (short)f2bf(a.z * QSCALE); w[3] = (short)f2bf(a.w * QSCALE);
      w[4] = (short)f2bf(c.x * QSCALE); w[5] = (short)f2bf(c.y * QSCALE);
      w[6] = (short)f2bf(c.z * QSCALE); w[7] = (short)f2bf(c.w * QSCALE);
      qf[t] = w;
    }
  }

  // loop-invariant fragment offsets (element units within a tile)
  const int rowb = l31 << 7;
  int ca[4], cb[4];
#pragma unroll
  for (int t = 0; t < 4; ++t) {
    int g = 2 * t + hi;
    ca[t] = rowb + (((g)     ^ (l31 & 15)) << 3);   // rows 0..31  of tile
    cb[t] = rowb + (((8 + g) ^ (l31 & 15)) << 3);   // rows 32..63 of tile
  }

  f32x16 o0 = {}, o1 = {};
  float m = -__builtin_inff();
  float l = 0.f;

#define STAGE(T, B)                                                        \
  do {                                                                     \
    const char* gk = (const char*)(Kh + (size_t)(T) * KVB * 64);           \
    const char* gv = (const char*)(Vh + (size_t)(T) * KVB * 64);           \
    char* lk = (char*)&kt[(B)][0];                                         \
    char* lv = (char*)&vt[(B)][0];                                         \
    gload16(gk + (((wv)     * 64 + ln) << 4), lk + ((wv)     << 10));      \
    gload16(gk + (((wv + 4) * 64 + ln) << 4), lk + ((wv + 4) << 10));      \
    gload16(gv + (((wv)     * 64 + ln) << 4), lv + ((wv)     << 10));      \
    gload16(gv + (((wv + 4) * 64 + ln) << 4), lv + ((wv + 4) << 10));      \
  } while (0)

  auto tile_compute = [&](const unsigned short* ktb, const unsigned short* vtb) {
    // ---- S^T = K Q^T ----
    f32x16 s0 = {}, s1 = {};
#pragma unroll
    for (int ks = 0; ks < 4; ++ks) {
      bf16x8 k0 = *(const bf16x8*)&ktb[ca[ks]];
      bf16x8 k1 = *(const bf16x8*)&ktb[cb[ks]];
      __builtin_amdgcn_s_setprio(1);
      s0 = MFMA32(k0, qf[ks], s0);
      s1 = MFMA32(k1, qf[ks], s1);
      __builtin_amdgcn_s_setprio(0);
    }

    // ---- per-lane online softmax (one q-row per lane) ----
    float pm = fmaxf(s0[0], s0[1]);
#pragma unroll
    for (int j = 2; j < 16; ++j) pm = fmaxf(pm, s0[j]);
#pragma unroll
    for (int j = 0; j < 16; ++j) pm = fmaxf(pm, s1[j]);
    pm = fmaxf(pm, __shfl_xor(pm, 32));

    if (__any(pm > m + THR)) {
      float mn   = fmaxf(m, pm);
      float corr = EXPFN(m - mn);
      m = mn;
      l *= corr;
#pragma unroll
      for (int j = 0; j < 16; ++j) { o0[j] *= corr; o1[j] *= corr; }
    }

    // ---- P = exp(S - m) -> bf16 B-fragments via cvt_pk + permlane32_swap ----
#pragma unroll
    for (int ks = 0; ks < 4; ++ks) {
      float e[8];
#pragma unroll
      for (int j = 0; j < 8; ++j) {
        float sv = (ks < 2) ? s0[(ks & 1) * 8 + j] : s1[(ks & 1) * 8 + j];
        e[j] = EXPFN(sv - m);
      }
      l += ((e[0] + e[1]) + (e[2] + e[3])) + ((e[4] + e[5]) + (e[6] + e[7]));
      i32x2 r0 = plswap(cvtpk(e[0], e[1]), cvtpk(e[4], e[5]));
      i32x2 r1 = plswap(cvtpk(e[2], e[3]), cvtpk(e[6], e[7]));
      union { int i[4]; bf16x8 v; } pa;
      pa.i[0] = r0.x; pa.i[1] = r1.x; pa.i[2] = r0.y; pa.i[3] = r1.y;

      bf16x8 v0 = *(const bf16x8*)&vtb[ca[ks]];
      bf16x8 v1 = *(const bf16x8*)&vtb[cb[ks]];
      __builtin_amdgcn_s_setprio(1);
      o0 = MFMA32(v0, pa.v, o0);
      o1 = MFMA32(v1, pa.v, o1);
      __builtin_amdgcn_s_setprio(0);
    }
  };

  STAGE(0, 0);
  __syncthreads();

  for (int t = 0; t < SEQ / KVB; t += 2) {
    STAGE(t + 1, 1);                       // always valid (t+1 <= 31)
    tile_compute(kt[0], vt[0]);
    __syncthreads();
    if (t + 2 < SEQ / KVB) STAGE(t + 2, 0);
    tile_compute(kt[1], vt[1]);
    __syncthreads();
  }

  // ---- epilogue ----
  l += __shfl_xor(l, 32);
  float rinv = 1.0f / l;
  float* op = Oh + (size_t)q * DMODEL;
#pragma unroll
  for (int r4 = 0; r4 < 4; ++r4) {
    float4 w0, w1;
    w0.x = o0[4 * r4 + 0] * rinv; w0.y = o0[4 * r4 + 1] * rinv;
    w0.z = o0[4 * r4 + 2] * rinv; w0.w = o0[4 * r4 + 3] * rinv;
    w1.x = o1[4 * r4 + 0] * rinv; w1.y = o1[4 * r4 + 1] * rinv;
    w1.z = o1[4 * r4 + 2] * rinv; w1.w = o1[4 * r4 + 3] * rinv;
    *(float4*)(op + 8 * r4 + 4 * hi)      = w0;
    *(float4*)(op + 32 + 8 * r4 + 4 * hi) = w1;
  }
}

extern "C" void kernel_launch(void* const* d_in, const int* in_sizes, int n_in,
                              void* d_out, int out_size, void* d_ws, size_t ws_size,
                              hipStream_t stream) {
  const float* Q = (const float*)d_in[0];
  const float* K = (const float*)d_in[1];
  const float* V = (const float*)d_in[2];
  float* O = (float*)d_out;
  unsigned short* kb = (unsigned short*)d_ws;
  unsigned short* vb = kb + (size_t)32 * SEQ * 64;
  prep_kv<<<3072, 256, 0, stream>>>(K, V, kb, vb);
  fa_fwd<<<512, 256, 0, stream>>>(Q, kb, vb, O);
}